// Round 6
// baseline (1961.903 us; speedup 1.0000x reference)
//
#include <hip/hip_runtime.h>
#include <hip/hip_bf16.h>

typedef __hip_bfloat16 bf16;

#define N_ATOMS 10000
#define N_EDGES 200000

// ======== float region of ws (float offsets) ========
#define SCG   0        // 615 cg coeffs f32
#define SINV  616      // 296 inv per channel (+pad)
#define SS1P  1024     // 296*64 partials
#define SS2P  19968    // 5*64 partials
#define SWS2  20288    // 5 (+pad)
#define SINTS 20352    // int region starts here (float idx)
// ======== int region (offsets in ints, relative to SINTS) ========
#define IFLAG  0
#define ICOUNT 16      // 10000
#define IOFFS  10016   // 10001 (+pad)
#define ICURS  20032   // 10000
#define IELIST 30032   // small: 200000 ints | big: 400000 ints (int2)
#define INTS_END_SMALL 230032
#define INTS_END_BIG   430032
#define SXACC (SINTS + INTS_END_BIG)
#define BIG_FLOATS (SXACC + 952*N_ATOMS)      // ~39.9 MB (round-5: small path ran)

// ---- d_out element offsets ----
#define O0 0
#define O1 320000
#define O2 1040000
#define OY 1840000

__device__ __forceinline__ float b2f(bf16 x){ return __bfloat162float(x); }
__device__ __forceinline__ bf16  f2b(float x){ return __float2bfloat16(x); }

__device__ __forceinline__ float ldv(const float* p, int i){ return p[i]; }
__device__ __forceinline__ float ldv(const bf16*  p, int i){ return b2f(p[i]); }
__device__ __forceinline__ void  stv(float* p, int i, float v){ p[i] = v; }
__device__ __forceinline__ void  stv(bf16*  p, int i, float v){ p[i] = f2b(v); }

// Launder a pointer through an empty asm so LICM cannot prove coefficient
// loads loop-invariant. Round-5 PMC: SGPR_Count=112 (maxed) + ~370 MB/dispatch
// scratch traffic = ~615 hoisted wave-uniform CG loads spilling the SGPR file.
#define LAUNDER(p) asm volatile("" : "+s"(p))

template<typename T> __device__ __forceinline__ int dtid();
template<> __device__ __forceinline__ int dtid<bf16>(){ return 0; }
template<> __device__ __forceinline__ int dtid<float>(){ return 1; }

struct Ptrs15 { const void* p[15]; };
struct LinP   { const void* W[5]; const void* B[5]; };

__constant__ int c_cg_sizes[15] = {1,9,25,9,9,27,45,45,75,25,45,75,25,75,125};
__constant__ int c_fin[5]   = {72,80,40,72,32};
__constant__ int c_kout[5]  = {32,24,24,16,16};
__constant__ int c_yoff[5]  = {OY+0, OY+320000, OY+1040000, OY+1760000, OY+2560000};
__constant__ int c_numel[5] = {320000,720000,720000,800000,800000};
__constant__ int c_cum[6]   = {0,32,104,176,256,336};
__constant__ int c_xb[5]    = {0,72,312,432,792};
__constant__ int c_Ms[5]    = {1,3,3,5,5};

// ---------------- dtype probe ----------------
__global__ void k_probe(const unsigned short* rb0u, const unsigned short* embu,
                        int* flag) {
  int lane = threadIdx.x;
  int bad = 0;
  for (int i = lane; i < 256; i += 64) {
    unsigned u1 = ((unsigned)rb0u[2*i]) << 16;
    unsigned u2 = ((unsigned)embu[2*i]) << 16;
    float v1 = __uint_as_float(u1);
    float v2 = __uint_as_float(u2);
    if (!(fabsf(v1) < 1e9f) || !(fabsf(v2) < 1e9f)) bad = 1;
  }
  unsigned long long any = __ballot(bad);
  if (lane == 0) flag[0] = (any != 0ULL) ? 1 : 0;   // 1 = fp32, 0 = bf16
}

__global__ void k_zero(float* wsf, int* wsi) {
  int i = blockIdx.x*blockDim.x + threadIdx.x;
  if (i < N_ATOMS) wsi[ICOUNT + i] = 0;
  int j = i - N_ATOMS;
  if (j >= 0 && j < N_ATOMS) wsi[ICURS + j] = 0;
  j -= N_ATOMS;
  if (j >= 0 && j < 18944) wsf[SS1P + j] = 0.f;
  j -= 18944;
  if (j >= 0 && j < 325) wsf[SS2P + j] = 0.f;
}

template<typename T>
__global__ void k_cg(Ptrs15 cg, float* wsf, const int* flag) {
  if (flag[0] != dtid<T>()) return;
  int i = blockIdx.x*blockDim.x + threadIdx.x;
  if (i >= 615) return;
  int s = 0, off = i;
  while (off >= c_cg_sizes[s]) { off -= c_cg_sizes[s]; ++s; }
  wsf[SCG + i] = ldv((const T*)cg.p[s], off);
}

__global__ void k_hist(const int* __restrict__ centers, int* __restrict__ counts) {
  int e = blockIdx.x*blockDim.x + threadIdx.x;
  if (e < N_EDGES) atomicAdd(&counts[centers[e]], 1);
}

__global__ void k_scan(const int* __restrict__ counts, int* __restrict__ offs) {
  __shared__ int part[1024];
  int t = threadIdx.x;
  int base = t*10;
  int s = 0;
  for (int i = 0; i < 10; ++i) { int idx = base+i; if (idx < N_ATOMS) s += counts[idx]; }
  part[t] = s;
  __syncthreads();
  for (int d = 1; d < 1024; d <<= 1) {
    int v = part[t];
    int add = (t >= d) ? part[t-d] : 0;
    __syncthreads();
    part[t] = v + add;
    __syncthreads();
  }
  int run = (t == 0) ? 0 : part[t-1];
  for (int i = 0; i < 10; ++i) {
    int idx = base+i;
    if (idx < N_ATOMS) { offs[idx] = run; run += counts[idx]; }
  }
  if (t == 1023) offs[N_ATOMS] = part[1023];
}

__global__ void k_scatter(const int* __restrict__ centers, const int* __restrict__ offs,
                          int* __restrict__ cursors, int* __restrict__ elist) {
  int e = blockIdx.x*blockDim.x + threadIdx.x;
  if (e < N_EDGES) {
    int c = centers[e];
    int p = atomicAdd(&cursors[c], 1);
    elist[offs[c] + p] = e;
  }
}

__global__ void k_scatter2(const int* __restrict__ centers, const int* __restrict__ neighbors,
                           const int* __restrict__ offs, int* __restrict__ cursors,
                           int2* __restrict__ elist2) {
  int e = blockIdx.x*blockDim.x + threadIdx.x;
  if (e < N_EDGES) {
    int c = centers[e];
    int p = atomicAdd(&cursors[c], 1);
    elist2[offs[c] + p] = make_int2(e, neighbors[e]);
  }
}

// ---------------- main K-loop: 4 waves/block, one atom per wave ----------------
// MODE 0: big ws — densities + s1p partials + raw-x store (int2 elist)
// MODE 1: small ws pass1 — densities + s1p partials
// MODE 2: small ws pass2 — recompute, normalize+linear, y + y^2
template<typename T, int MODE>
__global__ __launch_bounds__(256, 4) void k_main(
    const T* __restrict__ rb0, const T* __restrict__ rb1, const T* __restrict__ rb2,
    const T* __restrict__ sh0, const T* __restrict__ sh1, const T* __restrict__ sh2,
    const T* __restrict__ emb, const T* __restrict__ f0, const T* __restrict__ f1,
    const T* __restrict__ f2, const int* __restrict__ neighbors,
    const int* __restrict__ offs, const int* __restrict__ elist,
    const float* __restrict__ cgf, float* __restrict__ s1p,
    const float* __restrict__ inv, float* __restrict__ s2p,
    float* __restrict__ xout, LinP lp, T* __restrict__ out,
    const int* __restrict__ flag)
{
  if (flag[0] != dtid<T>()) return;
  int lane = threadIdx.x & 63;
  int wv   = threadIdx.x >> 6;
  int a = blockIdx.x*4 + wv;
  int beg = offs[a];
  int cnt = offs[a+1] - beg;
  int k32 = lane & 31, e2 = lane >> 5;
  int k16 = lane & 15, e4 = lane >> 4;
  const int2* el2 = (const int2*)elist;

  float accA[20];
  float accB[40];
  #pragma unroll
  for (int i = 0; i < 20; ++i) accA[i] = 0.f;
  #pragma unroll
  for (int i = 0; i < 40; ++i) accB[i] = 0.f;

  for (int base = 0; base < cnt; base += 4) {
    // Per-iteration laundered coefficient pointer for phase A (~100 values,
    // CSE'd across the two sub-passes but reloaded every iteration).
    const float* cga = cgf; LAUNDER(cga);
    const float* C000 = cga + 0;
    const float* C011 = cga + 1;
    const float* C101 = cga + 35;
    const float* C110 = cga + 44;
    const float* C111 = cga + 53;
    const float* C112 = cga + 80;

    // ---- phase A: lanes (e2, k32), 2 sub-passes cover 4 edges ----
    #pragma unroll
    for (int s = 0; s < 2; ++s) {
      int idx = base + 2*s + e2;
      if (idx < cnt) {
        int e, n;
        if constexpr (MODE == 0) { int2 en = el2[beg + idx]; e = en.x; n = en.y; }
        else { e = elist[beg + idx]; n = neighbors[e]; }
        float s0 = ldv(sh0, e);
        float s1a0 = ldv(sh1, e*3+0), s1a1 = ldv(sh1, e*3+1), s1a2 = ldv(sh1, e*3+2);
        float rb0k = ldv(rb0, e*32 + k32);
        float ek   = ldv(emb, n*32 + k32);
        float f0k  = ldv(f0,  n*32 + k32);
        float ve0 = s0 * rb0k;
        accA[0] = fmaf(ve0, ek, accA[0]);
        accA[4] = fmaf(C000[0]*ve0, f0k, accA[4]);
        if (k32 < 24) {
          float rb1k = ldv(rb1, e*24 + k32);
          float f1k0 = ldv(f1, n*72 + k32);
          float f1k1 = ldv(f1, n*72 + 24 + k32);
          float f1k2 = ldv(f1, n*72 + 48 + k32);
          float rbek = rb1k * ek;
          accA[1] = fmaf(s1a0, rbek, accA[1]);
          accA[2] = fmaf(s1a1, rbek, accA[2]);
          accA[3] = fmaf(s1a2, rbek, accA[3]);
          // (0,1,1)
          #pragma unroll
          for (int bb = 0; bb < 3; ++bb) {
            float fb = (bb==0)?f1k0:(bb==1)?f1k1:f1k2;
            float p = ve0 * fb;
            #pragma unroll
            for (int M = 0; M < 3; ++M) accA[5+M] = fmaf(p, C011[bb*3+M], accA[5+M]);
          }
          // (1,0,1)
          float g3 = rb1k * f0k;
          #pragma unroll
          for (int aa = 0; aa < 3; ++aa) {
            float sa = (aa==0)?s1a0:(aa==1)?s1a1:s1a2;
            float p = g3 * sa;
            #pragma unroll
            for (int M = 0; M < 3; ++M) accA[8+M] = fmaf(p, C101[aa*3+M], accA[8+M]);
          }
          // (1,1,0)+(1,1,1): 36 coeffs
          #pragma unroll
          for (int aa = 0; aa < 3; ++aa) {
            float sa = rb1k * ((aa==0)?s1a0:(aa==1)?s1a1:s1a2);
            #pragma unroll
            for (int bb = 0; bb < 3; ++bb) {
              float fb = (bb==0)?f1k0:(bb==1)?f1k1:f1k2;
              float p = sa * fb;
              int q = aa*3+bb;
              accA[11] = fmaf(p, C110[q], accA[11]);
              #pragma unroll
              for (int M = 0; M < 3; ++M) accA[12+M] = fmaf(p, C111[q*3+M], accA[12+M]);
            }
          }
          // (1,1,2): 45 coeffs
          #pragma unroll
          for (int aa = 0; aa < 3; ++aa) {
            float sa = rb1k * ((aa==0)?s1a0:(aa==1)?s1a1:s1a2);
            #pragma unroll
            for (int bb = 0; bb < 3; ++bb) {
              float fb = (bb==0)?f1k0:(bb==1)?f1k1:f1k2;
              float p = sa * fb;
              int q = aa*3+bb;
              #pragma unroll
              for (int M = 0; M < 5; ++M) accA[15+M] = fmaf(p, C112[q*5+M], accA[15+M]);
            }
          }
        }
      }
    }
    // ---- phase B: lanes (e4, k16), one pass covers 4 edges ----
    {
      int idx = base + e4;
      if (idx < cnt) {
        int e, n;
        if constexpr (MODE == 0) { int2 en = el2[beg + idx]; e = en.x; n = en.y; }
        else { e = elist[beg + idx]; n = neighbors[e]; }
        float s0 = ldv(sh0, e);
        float s1a[3];
        #pragma unroll
        for (int m = 0; m < 3; ++m) s1a[m] = ldv(sh1, e*3+m);
        float s2a[5];
        #pragma unroll
        for (int m = 0; m < 5; ++m) s2a[m] = ldv(sh2, e*5+m);
        float rb0k = ldv(rb0, e*32 + k16);
        float rb1k = ldv(rb1, e*24 + k16);
        float rb2k = ldv(rb2, e*16 + k16);
        float ek   = ldv(emb, n*32 + k16);
        float f0k  = ldv(f0,  n*32 + k16);
        float f1k[3];
        #pragma unroll
        for (int b = 0; b < 3; ++b) f1k[b] = ldv(f1, n*72 + b*24 + k16);
        float f2k[5];
        #pragma unroll
        for (int b = 0; b < 5; ++b) f2k[b] = ldv(f2, n*80 + b*16 + k16);
        float re = rb2k * ek;
        #pragma unroll
        for (int m = 0; m < 5; ++m) accB[m] = fmaf(s2a[m], re, accB[m]);
        float ve0 = s0 * rb0k;
        { // (0,2,2): 25 coeffs
          const float* cp = cgf; LAUNDER(cp);
          const float* C022 = cp + 10;
          #pragma unroll
          for (int bb = 0; bb < 5; ++bb) {
            float p = ve0 * f2k[bb];
            #pragma unroll
            for (int M = 0; M < 5; ++M) accB[5+M] = fmaf(p, C022[bb*5+M], accB[5+M]);
          }
        }
        { // (1,2,1): 45 coeffs
          const float* cp = cgf; LAUNDER(cp);
          const float* C121 = cp + 125;
          #pragma unroll
          for (int aa = 0; aa < 3; ++aa) {
            float sa = rb1k * s1a[aa];
            #pragma unroll
            for (int bb = 0; bb < 5; ++bb) {
              float p = sa * f2k[bb];
              int q = aa*5+bb;
              #pragma unroll
              for (int M = 0; M < 3; ++M) accB[10+M] = fmaf(p, C121[q*3+M], accB[10+M]);
            }
          }
        }
        { // (1,2,2): 75 coeffs
          const float* cp = cgf; LAUNDER(cp);
          const float* C122 = cp + 170;
          #pragma unroll
          for (int aa = 0; aa < 3; ++aa) {
            float sa = rb1k * s1a[aa];
            #pragma unroll
            for (int bb = 0; bb < 5; ++bb) {
              float p = sa * f2k[bb];
              int q = aa*5+bb;
              #pragma unroll
              for (int M = 0; M < 5; ++M) accB[13+M] = fmaf(p, C122[q*5+M], accB[13+M]);
            }
          }
        }
        { // (2,0,2): 25 coeffs
          const float* cp = cgf; LAUNDER(cp);
          const float* C202 = cp + 245;
          float g9 = rb2k * f0k;
          #pragma unroll
          for (int aa = 0; aa < 5; ++aa) {
            float p = g9 * s2a[aa];
            #pragma unroll
            for (int M = 0; M < 5; ++M) accB[18+M] = fmaf(p, C202[aa*5+M], accB[18+M]);
          }
        }
        { // (2,1,1): 45 coeffs
          const float* cp = cgf; LAUNDER(cp);
          const float* C211 = cp + 270;
          #pragma unroll
          for (int aa = 0; aa < 5; ++aa) {
            float sa = rb2k * s2a[aa];
            #pragma unroll
            for (int bb = 0; bb < 3; ++bb) {
              float p = sa * f1k[bb];
              int q = aa*3+bb;
              #pragma unroll
              for (int M = 0; M < 3; ++M) accB[23+M] = fmaf(p, C211[q*3+M], accB[23+M]);
            }
          }
        }
        { // (2,1,2): 75 coeffs
          const float* cp = cgf; LAUNDER(cp);
          const float* C212 = cp + 315;
          #pragma unroll
          for (int aa = 0; aa < 5; ++aa) {
            float sa = rb2k * s2a[aa];
            #pragma unroll
            for (int bb = 0; bb < 3; ++bb) {
              float p = sa * f1k[bb];
              int q = aa*3+bb;
              #pragma unroll
              for (int M = 0; M < 5; ++M) accB[26+M] = fmaf(p, C212[q*5+M], accB[26+M]);
            }
          }
        }
        { // (2,2,0)+(2,2,1): 100 coeffs
          const float* cp = cgf; LAUNDER(cp);
          const float* C220 = cp + 390;
          const float* C221 = cp + 415;
          #pragma unroll
          for (int aa = 0; aa < 5; ++aa) {
            float sa = rb2k * s2a[aa];
            #pragma unroll
            for (int bb = 0; bb < 5; ++bb) {
              float p = sa * f2k[bb];
              int q = aa*5+bb;
              accB[31] = fmaf(p, C220[q], accB[31]);
              #pragma unroll
              for (int M = 0; M < 3; ++M) accB[32+M] = fmaf(p, C221[q*3+M], accB[32+M]);
            }
          }
        }
        { // (2,2,2): 125 coeffs
          const float* cp = cgf; LAUNDER(cp);
          const float* C222 = cp + 490;
          #pragma unroll
          for (int aa = 0; aa < 5; ++aa) {
            float sa = rb2k * s2a[aa];
            #pragma unroll
            for (int bb = 0; bb < 5; ++bb) {
              float p = sa * f2k[bb];
              int q = aa*5+bb;
              #pragma unroll
              for (int M = 0; M < 5; ++M) accB[35+M] = fmaf(p, C222[q*5+M], accB[35+M]);
            }
          }
        }
      }
    }
  }

  // cross-lane reduction (within each wave)
  #pragma unroll
  for (int i = 0; i < 20; ++i) accA[i] += __shfl_xor(accA[i], 32);
  #pragma unroll
  for (int i = 0; i < 40; ++i) {
    accB[i] += __shfl_xor(accB[i], 16);
    accB[i] += __shfl_xor(accB[i], 32);
  }

  if constexpr (MODE != 2) {
    if (lane < 32) {
      stv(out, O0 + a*32 + k32, accA[0]);
      if (k32 < 24) {
        #pragma unroll
        for (int m = 0; m < 3; ++m) stv(out, O1 + a*72 + m*24 + k32, accA[1+m]);
      }
    }
    if (lane < 16) {
      #pragma unroll
      for (int m = 0; m < 5; ++m) stv(out, O2 + a*80 + m*16 + k16, accB[m]);
    }
    int ab = a & 63;
    if (lane < 32) {
      atomicAdd(&s1p[(0+k32)*64+ab], accA[4]*accA[4]);
      if (k32 < 24) {
        atomicAdd(&s1p[(32+k32)*64+ab], accA[11]*accA[11]);
        float q;
        q = accA[5]*accA[5]+accA[6]*accA[6]+accA[7]*accA[7];
        atomicAdd(&s1p[(72+k32)*64+ab], q);
        q = accA[8]*accA[8]+accA[9]*accA[9]+accA[10]*accA[10];
        atomicAdd(&s1p[(96+k32)*64+ab], q);
        q = accA[12]*accA[12]+accA[13]*accA[13]+accA[14]*accA[14];
        atomicAdd(&s1p[(152+k32)*64+ab], q);
        q = accA[15]*accA[15]+accA[16]*accA[16]+accA[17]*accA[17]
          + accA[18]*accA[18]+accA[19]*accA[19];
        atomicAdd(&s1p[(208+k32)*64+ab], q);
      }
    }
    if (lane < 16) {
      float q;
      atomicAdd(&s1p[(56+k16)*64+ab], accB[31]*accB[31]);
      q = accB[10]*accB[10]+accB[11]*accB[11]+accB[12]*accB[12];
      atomicAdd(&s1p[(120+k16)*64+ab], q);
      q = accB[23]*accB[23]+accB[24]*accB[24]+accB[25]*accB[25];
      atomicAdd(&s1p[(136+k16)*64+ab], q);
      q = accB[32]*accB[32]+accB[33]*accB[33]+accB[34]*accB[34];
      atomicAdd(&s1p[(176+k16)*64+ab], q);
      q = accB[5]*accB[5]+accB[6]*accB[6]+accB[7]*accB[7]
        + accB[8]*accB[8]+accB[9]*accB[9];
      atomicAdd(&s1p[(192+k16)*64+ab], q);
      q = accB[18]*accB[18]+accB[19]*accB[19]+accB[20]*accB[20]
        + accB[21]*accB[21]+accB[22]*accB[22];
      atomicAdd(&s1p[(232+k16)*64+ab], q);
      q = accB[35]*accB[35]+accB[36]*accB[36]+accB[37]*accB[37]
        + accB[38]*accB[38]+accB[39]*accB[39];
      atomicAdd(&s1p[(248+k16)*64+ab], q);
      q = accB[13]*accB[13]+accB[14]*accB[14]+accB[15]*accB[15]
        + accB[16]*accB[16]+accB[17]*accB[17];
      atomicAdd(&s1p[(264+k16)*64+ab], q);
      q = accB[26]*accB[26]+accB[27]*accB[27]+accB[28]*accB[28]
        + accB[29]*accB[29]+accB[30]*accB[30];
      atomicAdd(&s1p[(280+k16)*64+ab], q);
    }
  }

  if constexpr (MODE == 0) {
    float* xg = xout + a*952;
    if (lane < 32) {
      xg[k32] = accA[4];
      if (k32 < 24) {
        xg[32+k32] = accA[11];
        #pragma unroll
        for (int M = 0; M < 3; ++M) xg[72+M*80+k32]     = accA[5+M];
        #pragma unroll
        for (int M = 0; M < 3; ++M) xg[72+M*80+24+k32]  = accA[8+M];
        #pragma unroll
        for (int M = 0; M < 3; ++M) xg[312+M*40+k32]    = accA[12+M];
        #pragma unroll
        for (int M = 0; M < 5; ++M) xg[432+M*72+16+k32] = accA[15+M];
      }
    }
    if (lane < 16) {
      xg[56+k16] = accB[31];
      #pragma unroll
      for (int M = 0; M < 3; ++M) xg[72+M*80+48+k16]  = accB[10+M];
      #pragma unroll
      for (int M = 0; M < 3; ++M) xg[72+M*80+64+k16]  = accB[23+M];
      #pragma unroll
      for (int M = 0; M < 3; ++M) xg[312+M*40+24+k16] = accB[32+M];
      #pragma unroll
      for (int M = 0; M < 5; ++M) xg[432+M*72+k16]    = accB[5+M];
      #pragma unroll
      for (int M = 0; M < 5; ++M) xg[432+M*72+40+k16] = accB[18+M];
      #pragma unroll
      for (int M = 0; M < 5; ++M) xg[432+M*72+56+k16] = accB[35+M];
      #pragma unroll
      for (int M = 0; M < 5; ++M) xg[792+M*32+k16]    = accB[13+M];
      #pragma unroll
      for (int M = 0; M < 5; ++M) xg[792+M*32+16+k16] = accB[26+M];
    }
  }

  if constexpr (MODE == 2) {
    __shared__ float Lx[4][952];
    float* L = Lx[wv];
    if (lane < 32) {
      L[k32] = accA[4]*inv[k32];
      if (k32 < 24) {
        L[32+k32] = accA[11]*inv[32+k32];
        #pragma unroll
        for (int M = 0; M < 3; ++M) L[72+M*80+k32]     = accA[5+M]*inv[72+k32];
        #pragma unroll
        for (int M = 0; M < 3; ++M) L[72+M*80+24+k32]  = accA[8+M]*inv[96+k32];
        #pragma unroll
        for (int M = 0; M < 3; ++M) L[312+M*40+k32]    = accA[12+M]*inv[152+k32];
        #pragma unroll
        for (int M = 0; M < 5; ++M) L[432+M*72+16+k32] = accA[15+M]*inv[208+k32];
      }
    }
    if (lane < 16) {
      L[56+k16] = accB[31]*inv[56+k16];
      #pragma unroll
      for (int M = 0; M < 3; ++M) L[72+M*80+48+k16]  = accB[10+M]*inv[120+k16];
      #pragma unroll
      for (int M = 0; M < 3; ++M) L[72+M*80+64+k16]  = accB[23+M]*inv[136+k16];
      #pragma unroll
      for (int M = 0; M < 3; ++M) L[312+M*40+24+k16] = accB[32+M]*inv[176+k16];
      #pragma unroll
      for (int M = 0; M < 5; ++M) L[432+M*72+k16]    = accB[5+M]*inv[192+k16];
      #pragma unroll
      for (int M = 0; M < 5; ++M) L[432+M*72+40+k16] = accB[18+M]*inv[232+k16];
      #pragma unroll
      for (int M = 0; M < 5; ++M) L[432+M*72+56+k16] = accB[35+M]*inv[248+k16];
      #pragma unroll
      for (int M = 0; M < 5; ++M) L[792+M*32+k16]    = accB[13+M]*inv[264+k16];
      #pragma unroll
      for (int M = 0; M < 5; ++M) L[792+M*32+16+k16] = accB[26+M]*inv[280+k16];
    }
    __syncthreads();
    float y2[5] = {0.f,0.f,0.f,0.f,0.f};
    for (int tau = lane; tau < 336; tau += 64) {
      int ls = 0;
      while (tau >= c_cum[ls+1]) ++ls;
      int rem = tau - c_cum[ls];
      int kn = c_kout[ls], fin = c_fin[ls];
      int M = rem / kn, ko = rem - M*kn;
      const T* W = (const T*)lp.W[ls];
      float y = ldv((const T*)lp.B[ls], ko);
      const float* xv = &L[c_xb[ls] + M*fin];
      for (int f = 0; f < fin; ++f) y = fmaf(xv[f], ldv(W, f*kn+ko), y);
      stv(out, c_yoff[ls] + (a*c_Ms[ls] + M)*kn + ko, y);
      y2[ls] += y*y;
    }
    #pragma unroll
    for (int i = 0; i < 5; ++i) {
      y2[i] += __shfl_xor(y2[i], 1);  y2[i] += __shfl_xor(y2[i], 2);
      y2[i] += __shfl_xor(y2[i], 4);  y2[i] += __shfl_xor(y2[i], 8);
      y2[i] += __shfl_xor(y2[i], 16); y2[i] += __shfl_xor(y2[i], 32);
    }
    if (lane == 0) {
      #pragma unroll
      for (int i = 0; i < 5; ++i) atomicAdd(&s2p[i*64 + (a & 63)], y2[i]);
    }
  }
}

// ---------------- big path: normalize + linear from stored x ----------------
template<typename T>
__global__ __launch_bounds__(256) void k_lin(
    const float* __restrict__ xg, const float* __restrict__ inv,
    LinP lp, T* __restrict__ out, float* __restrict__ s2p,
    const int* __restrict__ flag)
{
  if (flag[0] != dtid<T>()) return;
  int a = blockIdx.x;
  int t = threadIdx.x;
  __shared__ float L[952];
  for (int i = t; i < 952; i += 256) {
    int ch;
    if      (i < 72)  ch = i;
    else if (i < 312) ch = 72  + (i-72)  % 80;
    else if (i < 432) ch = 152 + (i-312) % 40;
    else if (i < 792) ch = 192 + (i-432) % 72;
    else              ch = 264 + (i-792) % 32;
    L[i] = xg[a*952 + i] * inv[ch];
  }
  __syncthreads();
  float y2[5] = {0.f,0.f,0.f,0.f,0.f};
  for (int tau = t; tau < 336; tau += 256) {
    int ls = 0;
    while (tau >= c_cum[ls+1]) ++ls;
    int rem = tau - c_cum[ls];
    int kn = c_kout[ls], fin = c_fin[ls];
    int M = rem / kn, ko = rem - M*kn;
    const T* W = (const T*)lp.W[ls];
    float y = ldv((const T*)lp.B[ls], ko);
    const float* xv = &L[c_xb[ls] + M*fin];
    for (int f = 0; f < fin; ++f) y = fmaf(xv[f], ldv(W, f*kn+ko), y);
    stv(out, c_yoff[ls] + (a*c_Ms[ls] + M)*kn + ko, y);
    y2[ls] += y*y;
  }
  __shared__ float red[4][5];
  #pragma unroll
  for (int i = 0; i < 5; ++i) {
    y2[i] += __shfl_xor(y2[i], 1);  y2[i] += __shfl_xor(y2[i], 2);
    y2[i] += __shfl_xor(y2[i], 4);  y2[i] += __shfl_xor(y2[i], 8);
    y2[i] += __shfl_xor(y2[i], 16); y2[i] += __shfl_xor(y2[i], 32);
  }
  if ((t & 63) == 0) {
    #pragma unroll
    for (int i = 0; i < 5; ++i) red[t>>6][i] = y2[i];
  }
  __syncthreads();
  if (t == 0) {
    #pragma unroll
    for (int i = 0; i < 5; ++i)
      atomicAdd(&s2p[i*64 + (a & 63)], red[0][i]+red[1][i]+red[2][i]+red[3][i]);
  }
}

// ---------------- reducers ----------------
__global__ void k_red1(const float* __restrict__ s1p, float* __restrict__ inv) {
  int ch = blockIdx.x, lane = threadIdx.x;
  float v = s1p[ch*64 + lane];
  v += __shfl_xor(v, 1);  v += __shfl_xor(v, 2);  v += __shfl_xor(v, 4);
  v += __shfl_xor(v, 8);  v += __shfl_xor(v, 16); v += __shfl_xor(v, 32);
  if (lane == 0) {
    float rows = (ch < 72) ? 10000.f : (ch < 192) ? 30000.f : 50000.f;
    inv[ch] = rsqrtf(v/rows + 1e-12f);
  }
}

__global__ void k_red2(const float* __restrict__ s2p, float* __restrict__ ws2) {
  int ls = blockIdx.x, lane = threadIdx.x;
  float v = s2p[ls*64 + lane];
  v += __shfl_xor(v, 1);  v += __shfl_xor(v, 2);  v += __shfl_xor(v, 4);
  v += __shfl_xor(v, 8);  v += __shfl_xor(v, 16); v += __shfl_xor(v, 32);
  if (lane == 0) ws2[ls] = v;
}

// ---------------- final global RMS scale, in place ----------------
template<typename T>
__global__ void k_scale(const float* __restrict__ ws2, T* __restrict__ out,
                        const int* __restrict__ flag) {
  if (flag[0] != dtid<T>()) return;
  int i = blockIdx.x*blockDim.x + threadIdx.x;
  if (i >= 3360000) return;
  int ls = (i < 320000) ? 0 : (i < 1040000) ? 1 : (i < 1760000) ? 2 : (i < 2560000) ? 3 : 4;
  float scale = rsqrtf(ws2[ls] / (float)c_numel[ls] + 1e-12f);
  stv(out, OY + i, ldv((const T*)out, OY + i) * scale);
}

template<typename T>
static void launch_chain(void* const* d_in, T* out, float* wsf, int* wsi,
                         Ptrs15 cg, LinP lp, bool big, hipStream_t stream) {
  const T* rb0 = (const T*)d_in[0];
  const T* rb1 = (const T*)d_in[1];
  const T* rb2 = (const T*)d_in[2];
  const T* sh0 = (const T*)d_in[3];
  const T* sh1 = (const T*)d_in[4];
  const T* sh2 = (const T*)d_in[5];
  const T* emb = (const T*)d_in[6];
  const T* f0  = (const T*)d_in[7];
  const T* f1  = (const T*)d_in[8];
  const T* f2  = (const T*)d_in[9];
  const int* neighbors = (const int*)d_in[36];
  const int* flag = wsi + IFLAG;

  k_cg<T><<<3, 256, 0, stream>>>(cg, wsf, flag);
  if (big) {
    k_main<T,0><<<N_ATOMS/4, 256, 0, stream>>>(rb0, rb1, rb2, sh0, sh1, sh2, emb, f0, f1, f2,
        neighbors, wsi+IOFFS, wsi+IELIST, wsf+SCG, wsf+SS1P, nullptr, nullptr,
        wsf+SXACC, lp, out, flag);
    k_red1<<<296, 64, 0, stream>>>(wsf+SS1P, wsf+SINV);
    k_lin<T><<<N_ATOMS, 256, 0, stream>>>(wsf+SXACC, wsf+SINV, lp, out, wsf+SS2P, flag);
  } else {
    k_main<T,1><<<N_ATOMS/4, 256, 0, stream>>>(rb0, rb1, rb2, sh0, sh1, sh2, emb, f0, f1, f2,
        neighbors, wsi+IOFFS, wsi+IELIST, wsf+SCG, wsf+SS1P, nullptr, nullptr,
        nullptr, lp, out, flag);
    k_red1<<<296, 64, 0, stream>>>(wsf+SS1P, wsf+SINV);
    k_main<T,2><<<N_ATOMS/4, 256, 0, stream>>>(rb0, rb1, rb2, sh0, sh1, sh2, emb, f0, f1, f2,
        neighbors, wsi+IOFFS, wsi+IELIST, wsf+SCG, nullptr, wsf+SINV, wsf+SS2P,
        nullptr, lp, out, flag);
  }
  k_red2<<<5, 64, 0, stream>>>(wsf+SS2P, wsf+SWS2);
  k_scale<T><<<(3360000+255)/256, 256, 0, stream>>>(wsf+SWS2, out, flag);
}

extern "C" void kernel_launch(void* const* d_in, const int* in_sizes, int n_in,
                              void* d_out, int out_size, void* d_ws, size_t ws_size,
                              hipStream_t stream) {
  float* wsf = (float*)d_ws;
  int*   wsi = (int*)(wsf + SINTS);
  const int* centers   = (const int*)d_in[35];
  const int* neighbors = (const int*)d_in[36];
  bool big = ws_size >= (size_t)BIG_FLOATS * 4;

  Ptrs15 cg;
  for (int i = 0; i < 15; ++i) cg.p[i] = d_in[10+i];
  LinP lp;
  lp.W[0] = d_in[25]; lp.B[0] = d_in[26];
  lp.W[1] = d_in[27]; lp.B[1] = d_in[28];
  lp.W[2] = d_in[29]; lp.B[2] = d_in[30];
  lp.W[3] = d_in[31]; lp.B[3] = d_in[32];
  lp.W[4] = d_in[33]; lp.B[4] = d_in[34];

  k_probe<<<1, 64, 0, stream>>>((const unsigned short*)d_in[0],
                                (const unsigned short*)d_in[6], wsi + IFLAG);
  k_zero<<<154, 256, 0, stream>>>(wsf, wsi);
  k_hist<<<(N_EDGES+255)/256, 256, 0, stream>>>(centers, wsi+ICOUNT);
  k_scan<<<1, 1024, 0, stream>>>(wsi+ICOUNT, wsi+IOFFS);
  if (big) {
    k_scatter2<<<(N_EDGES+255)/256, 256, 0, stream>>>(centers, neighbors, wsi+IOFFS,
                                                      wsi+ICURS, (int2*)(wsi+IELIST));
  } else {
    k_scatter<<<(N_EDGES+255)/256, 256, 0, stream>>>(centers, wsi+IOFFS, wsi+ICURS, wsi+IELIST);
  }

  launch_chain<bf16 >(d_in, (bf16*)d_out,  wsf, wsi, cg, lp, big, stream);
  launch_chain<float>(d_in, (float*)d_out, wsf, wsi, cg, lp, big, stream);
}

// Round 7
// 516.357 us; speedup vs baseline: 3.7995x; 3.7995x over previous
//
#include <hip/hip_runtime.h>
#include <hip/hip_bf16.h>

typedef __hip_bfloat16 bf16;

#define N_ATOMS 10000
#define N_EDGES 200000

// ======== float region of ws (float offsets) ========
#define SCG   0        // 615 cg coeffs f32
#define SINV  616      // 296 inv per channel (+pad)
#define SS1P  1024     // 296*64 partials
#define SS2P  19968    // 5*64 partials
#define SWS2  20288    // 5 (+pad)
#define SINTS 20352    // int region starts here (float idx)
// ======== int region (offsets in ints, relative to SINTS) ========
#define IFLAG  0
#define ICOUNT 16      // 10000
#define IOFFS  10016   // 10001 (+pad)
#define ICURS  20032   // 10000
#define IELIST 30032   // small: 200000 ints | big: 400000 ints (int2)
#define INTS_END_SMALL 230032
#define INTS_END_BIG   430032
#define SXACC (SINTS + INTS_END_BIG)
#define BIG_FLOATS (SXACC + 952*N_ATOMS)      // ~39.9 MB

// ---- d_out element offsets ----
#define O0 0
#define O1 320000
#define O2 1040000
#define OY 1840000

__device__ __forceinline__ float b2f(bf16 x){ return __bfloat162float(x); }
__device__ __forceinline__ bf16  f2b(float x){ return __float2bfloat16(x); }

__device__ __forceinline__ float ldv(const float* p, int i){ return p[i]; }
__device__ __forceinline__ float ldv(const bf16*  p, int i){ return b2f(p[i]); }
__device__ __forceinline__ void  stv(float* p, int i, float v){ p[i] = v; }
__device__ __forceinline__ void  stv(bf16*  p, int i, float v){ p[i] = f2b(v); }

template<typename T> __device__ __forceinline__ int dtid();
template<> __device__ __forceinline__ int dtid<bf16>(){ return 0; }
template<> __device__ __forceinline__ int dtid<float>(){ return 1; }

struct Ptrs15 { const void* p[15]; };
struct LinP   { const void* W[5]; const void* B[5]; };

__constant__ int c_cg_sizes[15] = {1,9,25,9,9,27,45,45,75,25,45,75,25,75,125};
__constant__ int c_fin[5]   = {72,80,40,72,32};
__constant__ int c_kout[5]  = {32,24,24,16,16};
__constant__ int c_yoff[5]  = {OY+0, OY+320000, OY+1040000, OY+1760000, OY+2560000};
__constant__ int c_numel[5] = {320000,720000,720000,800000,800000};
__constant__ int c_cum[6]   = {0,32,104,176,256,336};
__constant__ int c_xb[5]    = {0,72,312,432,792};
__constant__ int c_Ms[5]    = {1,3,3,5,5};

// ---------------- dtype probe ----------------
__global__ void k_probe(const unsigned short* rb0u, const unsigned short* embu,
                        int* flag) {
  int lane = threadIdx.x;
  int bad = 0;
  for (int i = lane; i < 256; i += 64) {
    unsigned u1 = ((unsigned)rb0u[2*i]) << 16;
    unsigned u2 = ((unsigned)embu[2*i]) << 16;
    float v1 = __uint_as_float(u1);
    float v2 = __uint_as_float(u2);
    if (!(fabsf(v1) < 1e9f) || !(fabsf(v2) < 1e9f)) bad = 1;
  }
  unsigned long long any = __ballot(bad);
  if (lane == 0) flag[0] = (any != 0ULL) ? 1 : 0;   // 1 = fp32, 0 = bf16
}

__global__ void k_zero(float* wsf, int* wsi) {
  int i = blockIdx.x*blockDim.x + threadIdx.x;
  if (i < N_ATOMS) wsi[ICOUNT + i] = 0;
  int j = i - N_ATOMS;
  if (j >= 0 && j < N_ATOMS) wsi[ICURS + j] = 0;
  j -= N_ATOMS;
  if (j >= 0 && j < 18944) wsf[SS1P + j] = 0.f;
  j -= 18944;
  if (j >= 0 && j < 325) wsf[SS2P + j] = 0.f;
}

template<typename T>
__global__ void k_cg(Ptrs15 cg, float* wsf, const int* flag) {
  if (flag[0] != dtid<T>()) return;
  int i = blockIdx.x*blockDim.x + threadIdx.x;
  if (i >= 615) return;
  int s = 0, off = i;
  while (off >= c_cg_sizes[s]) { off -= c_cg_sizes[s]; ++s; }
  wsf[SCG + i] = ldv((const T*)cg.p[s], off);
}

__global__ void k_hist(const int* __restrict__ centers, int* __restrict__ counts) {
  int e = blockIdx.x*blockDim.x + threadIdx.x;
  if (e < N_EDGES) atomicAdd(&counts[centers[e]], 1);
}

__global__ void k_scan(const int* __restrict__ counts, int* __restrict__ offs) {
  __shared__ int part[1024];
  int t = threadIdx.x;
  int base = t*10;
  int s = 0;
  for (int i = 0; i < 10; ++i) { int idx = base+i; if (idx < N_ATOMS) s += counts[idx]; }
  part[t] = s;
  __syncthreads();
  for (int d = 1; d < 1024; d <<= 1) {
    int v = part[t];
    int add = (t >= d) ? part[t-d] : 0;
    __syncthreads();
    part[t] = v + add;
    __syncthreads();
  }
  int run = (t == 0) ? 0 : part[t-1];
  for (int i = 0; i < 10; ++i) {
    int idx = base+i;
    if (idx < N_ATOMS) { offs[idx] = run; run += counts[idx]; }
  }
  if (t == 1023) offs[N_ATOMS] = part[1023];
}

__global__ void k_scatter(const int* __restrict__ centers, const int* __restrict__ offs,
                          int* __restrict__ cursors, int* __restrict__ elist) {
  int e = blockIdx.x*blockDim.x + threadIdx.x;
  if (e < N_EDGES) {
    int c = centers[e];
    int p = atomicAdd(&cursors[c], 1);
    elist[offs[c] + p] = e;
  }
}

__global__ void k_scatter2(const int* __restrict__ centers, const int* __restrict__ neighbors,
                           const int* __restrict__ offs, int* __restrict__ cursors,
                           int2* __restrict__ elist2) {
  int e = blockIdx.x*blockDim.x + threadIdx.x;
  if (e < N_EDGES) {
    int c = centers[e];
    int p = atomicAdd(&cursors[c], 1);
    elist2[offs[c] + p] = make_int2(e, neighbors[e]);
  }
}

// ---------------- main K-loop: 1 atom/block, 4 wave-specialized waves ----------
// Round-6 lesson: one lane holding all 60 accumulators spills ~30 regs/iter
// (~350 MB scratch traffic) at ANY launch-bounds setting. Split the 15 CG
// pairs across 4 waves so max live set ~45 VGPRs:
//   W0 (k32): d0,d1,p000,p011,p101,p110,p111,p112 (20 acc)
//   W1 (k16): d2,p022,p121,p122 (18) | W2: p202,p211,p212 (13) | W3: p220..2 (9)
// MODE 0: + raw-x store (int2 elist). MODE 1: densities+s1p. MODE 2: recompute,
// normalize+linear.  NO asm laundering (round-6: catastrophic).
template<typename T, int MODE>
__global__ __launch_bounds__(256) void k_main(
    const T* __restrict__ rb0, const T* __restrict__ rb1, const T* __restrict__ rb2,
    const T* __restrict__ sh0, const T* __restrict__ sh1, const T* __restrict__ sh2,
    const T* __restrict__ emb, const T* __restrict__ f0, const T* __restrict__ f1,
    const T* __restrict__ f2, const int* __restrict__ neighbors,
    const int* __restrict__ offs, const int* __restrict__ elist,
    const float* __restrict__ cgf, float* __restrict__ s1p,
    const float* __restrict__ inv, float* __restrict__ s2p,
    float* __restrict__ xout, LinP lp, T* __restrict__ out,
    const int* __restrict__ flag)
{
  if (flag[0] != dtid<T>()) return;
  int lane = threadIdx.x & 63;
  int wv   = threadIdx.x >> 6;
  int a = blockIdx.x;
  int beg = offs[a];
  int cnt = offs[a+1] - beg;
  int k32 = lane & 31, e2 = lane >> 5;
  int k16 = lane & 15, e4 = lane >> 4;
  const int2* el2 = (const int2*)elist;
  int ab = a & 63;

  __shared__ float L[952];
  __shared__ float red[4][5];

  float acc[20];
  #pragma unroll
  for (int i = 0; i < 20; ++i) acc[i] = 0.f;

  if (wv == 0) {
    // ---- W0: l1-sector pairs, lanes (e2,k32), 2 edges/iter ----
    const float* C000 = cgf + 0;
    const float* C011 = cgf + 1;
    const float* C101 = cgf + 35;
    const float* C110 = cgf + 44;
    const float* C111 = cgf + 53;
    const float* C112 = cgf + 80;
    for (int base = 0; base < cnt; base += 2) {
      int idx = base + e2;
      if (idx < cnt) {
        int e, n;
        if constexpr (MODE == 0) { int2 en = el2[beg + idx]; e = en.x; n = en.y; }
        else { e = elist[beg + idx]; n = neighbors[e]; }
        float s0 = ldv(sh0, e);
        float s1a0 = ldv(sh1, e*3+0), s1a1 = ldv(sh1, e*3+1), s1a2 = ldv(sh1, e*3+2);
        float rb0k = ldv(rb0, e*32 + k32);
        float ek   = ldv(emb, n*32 + k32);
        float f0k  = ldv(f0,  n*32 + k32);
        float ve0 = s0 * rb0k;
        acc[0] = fmaf(ve0, ek, acc[0]);
        acc[4] = fmaf(C000[0]*ve0, f0k, acc[4]);
        if (k32 < 24) {
          float rb1k = ldv(rb1, e*24 + k32);
          float f1k0 = ldv(f1, n*72 + k32);
          float f1k1 = ldv(f1, n*72 + 24 + k32);
          float f1k2 = ldv(f1, n*72 + 48 + k32);
          float rbek = rb1k * ek;
          acc[1] = fmaf(s1a0, rbek, acc[1]);
          acc[2] = fmaf(s1a1, rbek, acc[2]);
          acc[3] = fmaf(s1a2, rbek, acc[3]);
          #pragma unroll
          for (int bb = 0; bb < 3; ++bb) {
            float fb = (bb==0)?f1k0:(bb==1)?f1k1:f1k2;
            float p = ve0 * fb;
            #pragma unroll
            for (int M = 0; M < 3; ++M) acc[5+M] = fmaf(p, C011[bb*3+M], acc[5+M]);
          }
          float g3 = rb1k * f0k;
          #pragma unroll
          for (int aa = 0; aa < 3; ++aa) {
            float sa = (aa==0)?s1a0:(aa==1)?s1a1:s1a2;
            float p = g3 * sa;
            #pragma unroll
            for (int M = 0; M < 3; ++M) acc[8+M] = fmaf(p, C101[aa*3+M], acc[8+M]);
          }
          #pragma unroll
          for (int aa = 0; aa < 3; ++aa) {
            float sa = rb1k * ((aa==0)?s1a0:(aa==1)?s1a1:s1a2);
            #pragma unroll
            for (int bb = 0; bb < 3; ++bb) {
              float fb = (bb==0)?f1k0:(bb==1)?f1k1:f1k2;
              float p = sa * fb;
              int q = aa*3+bb;
              acc[11] = fmaf(p, C110[q], acc[11]);
              #pragma unroll
              for (int M = 0; M < 3; ++M) acc[12+M] = fmaf(p, C111[q*3+M], acc[12+M]);
              #pragma unroll
              for (int M = 0; M < 5; ++M) acc[15+M] = fmaf(p, C112[q*5+M], acc[15+M]);
            }
          }
        }
      }
    }
    #pragma unroll
    for (int i = 0; i < 20; ++i) acc[i] += __shfl_xor(acc[i], 32);
  } else if (wv == 1) {
    // ---- W1: d2 + (0,2,2),(1,2,1),(1,2,2), lanes (e4,k16), 4 edges/iter ----
    const float* C022 = cgf + 10;
    const float* C121 = cgf + 125;
    const float* C122 = cgf + 170;
    for (int base = 0; base < cnt; base += 4) {
      int idx = base + e4;
      if (idx < cnt) {
        int e, n;
        if constexpr (MODE == 0) { int2 en = el2[beg + idx]; e = en.x; n = en.y; }
        else { e = elist[beg + idx]; n = neighbors[e]; }
        float s0 = ldv(sh0, e);
        float s1a[3];
        #pragma unroll
        for (int m = 0; m < 3; ++m) s1a[m] = ldv(sh1, e*3+m);
        float s2a[5];
        #pragma unroll
        for (int m = 0; m < 5; ++m) s2a[m] = ldv(sh2, e*5+m);
        float rb0k = ldv(rb0, e*32 + k16);
        float rb1k = ldv(rb1, e*24 + k16);
        float rb2k = ldv(rb2, e*16 + k16);
        float ek   = ldv(emb, n*32 + k16);
        float f2k[5];
        #pragma unroll
        for (int b = 0; b < 5; ++b) f2k[b] = ldv(f2, n*80 + b*16 + k16);
        float re = rb2k * ek;
        #pragma unroll
        for (int m = 0; m < 5; ++m) acc[m] = fmaf(s2a[m], re, acc[m]);
        float ve0 = s0 * rb0k;
        #pragma unroll
        for (int bb = 0; bb < 5; ++bb) {
          float p = ve0 * f2k[bb];
          #pragma unroll
          for (int M = 0; M < 5; ++M) acc[5+M] = fmaf(p, C022[bb*5+M], acc[5+M]);
        }
        #pragma unroll
        for (int aa = 0; aa < 3; ++aa) {
          float sa = rb1k * s1a[aa];
          #pragma unroll
          for (int bb = 0; bb < 5; ++bb) {
            float p = sa * f2k[bb];
            int q = aa*5+bb;
            #pragma unroll
            for (int M = 0; M < 3; ++M) acc[10+M] = fmaf(p, C121[q*3+M], acc[10+M]);
            #pragma unroll
            for (int M = 0; M < 5; ++M) acc[13+M] = fmaf(p, C122[q*5+M], acc[13+M]);
          }
        }
      }
    }
    #pragma unroll
    for (int i = 0; i < 18; ++i) {
      acc[i] += __shfl_xor(acc[i], 16);
      acc[i] += __shfl_xor(acc[i], 32);
    }
  } else if (wv == 2) {
    // ---- W2: (2,0,2),(2,1,1),(2,1,2) ----
    const float* C202 = cgf + 245;
    const float* C211 = cgf + 270;
    const float* C212 = cgf + 315;
    for (int base = 0; base < cnt; base += 4) {
      int idx = base + e4;
      if (idx < cnt) {
        int e, n;
        if constexpr (MODE == 0) { int2 en = el2[beg + idx]; e = en.x; n = en.y; }
        else { e = elist[beg + idx]; n = neighbors[e]; }
        float s2a[5];
        #pragma unroll
        for (int m = 0; m < 5; ++m) s2a[m] = ldv(sh2, e*5+m);
        float rb2k = ldv(rb2, e*16 + k16);
        float f0k  = ldv(f0,  n*32 + k16);
        float f1k[3];
        #pragma unroll
        for (int b = 0; b < 3; ++b) f1k[b] = ldv(f1, n*72 + b*24 + k16);
        float g9 = rb2k * f0k;
        #pragma unroll
        for (int aa = 0; aa < 5; ++aa) {
          float p = g9 * s2a[aa];
          #pragma unroll
          for (int M = 0; M < 5; ++M) acc[0+M] = fmaf(p, C202[aa*5+M], acc[0+M]);
        }
        #pragma unroll
        for (int aa = 0; aa < 5; ++aa) {
          float sa = rb2k * s2a[aa];
          #pragma unroll
          for (int bb = 0; bb < 3; ++bb) {
            float p = sa * f1k[bb];
            int q = aa*3+bb;
            #pragma unroll
            for (int M = 0; M < 3; ++M) acc[5+M] = fmaf(p, C211[q*3+M], acc[5+M]);
            #pragma unroll
            for (int M = 0; M < 5; ++M) acc[8+M] = fmaf(p, C212[q*5+M], acc[8+M]);
          }
        }
      }
    }
    #pragma unroll
    for (int i = 0; i < 13; ++i) {
      acc[i] += __shfl_xor(acc[i], 16);
      acc[i] += __shfl_xor(acc[i], 32);
    }
  } else {
    // ---- W3: (2,2,0),(2,2,1),(2,2,2) ----
    const float* C220 = cgf + 390;
    const float* C221 = cgf + 415;
    const float* C222 = cgf + 490;
    for (int base = 0; base < cnt; base += 4) {
      int idx = base + e4;
      if (idx < cnt) {
        int e, n;
        if constexpr (MODE == 0) { int2 en = el2[beg + idx]; e = en.x; n = en.y; }
        else { e = elist[beg + idx]; n = neighbors[e]; }
        float s2a[5];
        #pragma unroll
        for (int m = 0; m < 5; ++m) s2a[m] = ldv(sh2, e*5+m);
        float rb2k = ldv(rb2, e*16 + k16);
        float f2k[5];
        #pragma unroll
        for (int b = 0; b < 5; ++b) f2k[b] = ldv(f2, n*80 + b*16 + k16);
        #pragma unroll
        for (int aa = 0; aa < 5; ++aa) {
          float sa = rb2k * s2a[aa];
          #pragma unroll
          for (int bb = 0; bb < 5; ++bb) {
            float p = sa * f2k[bb];
            int q = aa*5+bb;
            acc[0] = fmaf(p, C220[q], acc[0]);
            #pragma unroll
            for (int M = 0; M < 3; ++M) acc[1+M] = fmaf(p, C221[q*3+M], acc[1+M]);
            #pragma unroll
            for (int M = 0; M < 5; ++M) acc[4+M] = fmaf(p, C222[q*5+M], acc[4+M]);
          }
        }
      }
    }
    #pragma unroll
    for (int i = 0; i < 9; ++i) {
      acc[i] += __shfl_xor(acc[i], 16);
      acc[i] += __shfl_xor(acc[i], 32);
    }
  }

  // ---------------- epilogues ----------------
  if constexpr (MODE != 2) {
    if (wv == 0) {
      if (lane < 32) {
        stv(out, O0 + a*32 + k32, acc[0]);
        atomicAdd(&s1p[(0+k32)*64+ab], acc[4]*acc[4]);
        if (k32 < 24) {
          #pragma unroll
          for (int m = 0; m < 3; ++m) stv(out, O1 + a*72 + m*24 + k32, acc[1+m]);
          atomicAdd(&s1p[(32+k32)*64+ab], acc[11]*acc[11]);
          float q;
          q = acc[5]*acc[5]+acc[6]*acc[6]+acc[7]*acc[7];
          atomicAdd(&s1p[(72+k32)*64+ab], q);
          q = acc[8]*acc[8]+acc[9]*acc[9]+acc[10]*acc[10];
          atomicAdd(&s1p[(96+k32)*64+ab], q);
          q = acc[12]*acc[12]+acc[13]*acc[13]+acc[14]*acc[14];
          atomicAdd(&s1p[(152+k32)*64+ab], q);
          q = acc[15]*acc[15]+acc[16]*acc[16]+acc[17]*acc[17]
            + acc[18]*acc[18]+acc[19]*acc[19];
          atomicAdd(&s1p[(208+k32)*64+ab], q);
        }
      }
    } else if (wv == 1) {
      if (lane < 16) {
        #pragma unroll
        for (int m = 0; m < 5; ++m) stv(out, O2 + a*80 + m*16 + k16, acc[m]);
        float q;
        q = acc[5]*acc[5]+acc[6]*acc[6]+acc[7]*acc[7]+acc[8]*acc[8]+acc[9]*acc[9];
        atomicAdd(&s1p[(192+k16)*64+ab], q);
        q = acc[10]*acc[10]+acc[11]*acc[11]+acc[12]*acc[12];
        atomicAdd(&s1p[(120+k16)*64+ab], q);
        q = acc[13]*acc[13]+acc[14]*acc[14]+acc[15]*acc[15]
          + acc[16]*acc[16]+acc[17]*acc[17];
        atomicAdd(&s1p[(264+k16)*64+ab], q);
      }
    } else if (wv == 2) {
      if (lane < 16) {
        float q;
        q = acc[0]*acc[0]+acc[1]*acc[1]+acc[2]*acc[2]+acc[3]*acc[3]+acc[4]*acc[4];
        atomicAdd(&s1p[(232+k16)*64+ab], q);
        q = acc[5]*acc[5]+acc[6]*acc[6]+acc[7]*acc[7];
        atomicAdd(&s1p[(136+k16)*64+ab], q);
        q = acc[8]*acc[8]+acc[9]*acc[9]+acc[10]*acc[10]
          + acc[11]*acc[11]+acc[12]*acc[12];
        atomicAdd(&s1p[(280+k16)*64+ab], q);
      }
    } else {
      if (lane < 16) {
        atomicAdd(&s1p[(56+k16)*64+ab], acc[0]*acc[0]);
        float q;
        q = acc[1]*acc[1]+acc[2]*acc[2]+acc[3]*acc[3];
        atomicAdd(&s1p[(176+k16)*64+ab], q);
        q = acc[4]*acc[4]+acc[5]*acc[5]+acc[6]*acc[6]
          + acc[7]*acc[7]+acc[8]*acc[8];
        atomicAdd(&s1p[(248+k16)*64+ab], q);
      }
    }
  }

  if constexpr (MODE == 0) {
    float* xg = xout + a*952;
    if (wv == 0) {
      if (lane < 32) {
        xg[k32] = acc[4];
        if (k32 < 24) {
          xg[32+k32] = acc[11];
          #pragma unroll
          for (int M = 0; M < 3; ++M) xg[72+M*80+k32]     = acc[5+M];
          #pragma unroll
          for (int M = 0; M < 3; ++M) xg[72+M*80+24+k32]  = acc[8+M];
          #pragma unroll
          for (int M = 0; M < 3; ++M) xg[312+M*40+k32]    = acc[12+M];
          #pragma unroll
          for (int M = 0; M < 5; ++M) xg[432+M*72+16+k32] = acc[15+M];
        }
      }
    } else if (wv == 1) {
      if (lane < 16) {
        #pragma unroll
        for (int M = 0; M < 5; ++M) xg[432+M*72+k16]    = acc[5+M];
        #pragma unroll
        for (int M = 0; M < 3; ++M) xg[72+M*80+48+k16]  = acc[10+M];
        #pragma unroll
        for (int M = 0; M < 5; ++M) xg[792+M*32+k16]    = acc[13+M];
      }
    } else if (wv == 2) {
      if (lane < 16) {
        #pragma unroll
        for (int M = 0; M < 5; ++M) xg[432+M*72+40+k16] = acc[0+M];
        #pragma unroll
        for (int M = 0; M < 3; ++M) xg[72+M*80+64+k16]  = acc[5+M];
        #pragma unroll
        for (int M = 0; M < 5; ++M) xg[792+M*32+16+k16] = acc[8+M];
      }
    } else {
      if (lane < 16) {
        xg[56+k16] = acc[0];
        #pragma unroll
        for (int M = 0; M < 3; ++M) xg[312+M*40+24+k16] = acc[1+M];
        #pragma unroll
        for (int M = 0; M < 5; ++M) xg[432+M*72+56+k16] = acc[4+M];
      }
    }
  }

  if constexpr (MODE == 2) {
    if (wv == 0) {
      if (lane < 32) {
        L[k32] = acc[4]*inv[k32];
        if (k32 < 24) {
          L[32+k32] = acc[11]*inv[32+k32];
          #pragma unroll
          for (int M = 0; M < 3; ++M) L[72+M*80+k32]     = acc[5+M]*inv[72+k32];
          #pragma unroll
          for (int M = 0; M < 3; ++M) L[72+M*80+24+k32]  = acc[8+M]*inv[96+k32];
          #pragma unroll
          for (int M = 0; M < 3; ++M) L[312+M*40+k32]    = acc[12+M]*inv[152+k32];
          #pragma unroll
          for (int M = 0; M < 5; ++M) L[432+M*72+16+k32] = acc[15+M]*inv[208+k32];
        }
      }
    } else if (wv == 1) {
      if (lane < 16) {
        #pragma unroll
        for (int M = 0; M < 5; ++M) L[432+M*72+k16]    = acc[5+M]*inv[192+k16];
        #pragma unroll
        for (int M = 0; M < 3; ++M) L[72+M*80+48+k16]  = acc[10+M]*inv[120+k16];
        #pragma unroll
        for (int M = 0; M < 5; ++M) L[792+M*32+k16]    = acc[13+M]*inv[264+k16];
      }
    } else if (wv == 2) {
      if (lane < 16) {
        #pragma unroll
        for (int M = 0; M < 5; ++M) L[432+M*72+40+k16] = acc[0+M]*inv[232+k16];
        #pragma unroll
        for (int M = 0; M < 3; ++M) L[72+M*80+64+k16]  = acc[5+M]*inv[136+k16];
        #pragma unroll
        for (int M = 0; M < 5; ++M) L[792+M*32+16+k16] = acc[8+M]*inv[280+k16];
      }
    } else {
      if (lane < 16) {
        L[56+k16] = acc[0]*inv[56+k16];
        #pragma unroll
        for (int M = 0; M < 3; ++M) L[312+M*40+24+k16] = acc[1+M]*inv[176+k16];
        #pragma unroll
        for (int M = 0; M < 5; ++M) L[432+M*72+56+k16] = acc[4+M]*inv[248+k16];
      }
    }
    __syncthreads();
    int t = threadIdx.x;
    float y2[5] = {0.f,0.f,0.f,0.f,0.f};
    for (int tau = t; tau < 336; tau += 256) {
      int ls = 0;
      while (tau >= c_cum[ls+1]) ++ls;
      int rem = tau - c_cum[ls];
      int kn = c_kout[ls], fin = c_fin[ls];
      int M = rem / kn, ko = rem - M*kn;
      const T* W = (const T*)lp.W[ls];
      float y = ldv((const T*)lp.B[ls], ko);
      const float* xv = &L[c_xb[ls] + M*fin];
      for (int f = 0; f < fin; ++f) y = fmaf(xv[f], ldv(W, f*kn+ko), y);
      stv(out, c_yoff[ls] + (a*c_Ms[ls] + M)*kn + ko, y);
      y2[ls] += y*y;
    }
    #pragma unroll
    for (int i = 0; i < 5; ++i) {
      y2[i] += __shfl_xor(y2[i], 1);  y2[i] += __shfl_xor(y2[i], 2);
      y2[i] += __shfl_xor(y2[i], 4);  y2[i] += __shfl_xor(y2[i], 8);
      y2[i] += __shfl_xor(y2[i], 16); y2[i] += __shfl_xor(y2[i], 32);
    }
    if (lane == 0) {
      #pragma unroll
      for (int i = 0; i < 5; ++i) red[wv][i] = y2[i];
    }
    __syncthreads();
    if (t == 0) {
      #pragma unroll
      for (int i = 0; i < 5; ++i)
        atomicAdd(&s2p[i*64 + ab], red[0][i]+red[1][i]+red[2][i]+red[3][i]);
    }
  }
}

// ---------------- big path: normalize + linear from stored x ----------------
template<typename T>
__global__ __launch_bounds__(256) void k_lin(
    const float* __restrict__ xg, const float* __restrict__ inv,
    LinP lp, T* __restrict__ out, float* __restrict__ s2p,
    const int* __restrict__ flag)
{
  if (flag[0] != dtid<T>()) return;
  int a = blockIdx.x;
  int t = threadIdx.x;
  __shared__ float L[952];
  for (int i = t; i < 952; i += 256) {
    int ch;
    if      (i < 72)  ch = i;
    else if (i < 312) ch = 72  + (i-72)  % 80;
    else if (i < 432) ch = 152 + (i-312) % 40;
    else if (i < 792) ch = 192 + (i-432) % 72;
    else              ch = 264 + (i-792) % 32;
    L[i] = xg[a*952 + i] * inv[ch];
  }
  __syncthreads();
  float y2[5] = {0.f,0.f,0.f,0.f,0.f};
  for (int tau = t; tau < 336; tau += 256) {
    int ls = 0;
    while (tau >= c_cum[ls+1]) ++ls;
    int rem = tau - c_cum[ls];
    int kn = c_kout[ls], fin = c_fin[ls];
    int M = rem / kn, ko = rem - M*kn;
    const T* W = (const T*)lp.W[ls];
    float y = ldv((const T*)lp.B[ls], ko);
    const float* xv = &L[c_xb[ls] + M*fin];
    for (int f = 0; f < fin; ++f) y = fmaf(xv[f], ldv(W, f*kn+ko), y);
    stv(out, c_yoff[ls] + (a*c_Ms[ls] + M)*kn + ko, y);
    y2[ls] += y*y;
  }
  __shared__ float red[4][5];
  #pragma unroll
  for (int i = 0; i < 5; ++i) {
    y2[i] += __shfl_xor(y2[i], 1);  y2[i] += __shfl_xor(y2[i], 2);
    y2[i] += __shfl_xor(y2[i], 4);  y2[i] += __shfl_xor(y2[i], 8);
    y2[i] += __shfl_xor(y2[i], 16); y2[i] += __shfl_xor(y2[i], 32);
  }
  if ((t & 63) == 0) {
    #pragma unroll
    for (int i = 0; i < 5; ++i) red[t>>6][i] = y2[i];
  }
  __syncthreads();
  if (t == 0) {
    #pragma unroll
    for (int i = 0; i < 5; ++i)
      atomicAdd(&s2p[i*64 + (a & 63)], red[0][i]+red[1][i]+red[2][i]+red[3][i]);
  }
}

// ---------------- reducers ----------------
__global__ void k_red1(const float* __restrict__ s1p, float* __restrict__ inv) {
  int ch = blockIdx.x, lane = threadIdx.x;
  float v = s1p[ch*64 + lane];
  v += __shfl_xor(v, 1);  v += __shfl_xor(v, 2);  v += __shfl_xor(v, 4);
  v += __shfl_xor(v, 8);  v += __shfl_xor(v, 16); v += __shfl_xor(v, 32);
  if (lane == 0) {
    float rows = (ch < 72) ? 10000.f : (ch < 192) ? 30000.f : 50000.f;
    inv[ch] = rsqrtf(v/rows + 1e-12f);
  }
}

__global__ void k_red2(const float* __restrict__ s2p, float* __restrict__ ws2) {
  int ls = blockIdx.x, lane = threadIdx.x;
  float v = s2p[ls*64 + lane];
  v += __shfl_xor(v, 1);  v += __shfl_xor(v, 2);  v += __shfl_xor(v, 4);
  v += __shfl_xor(v, 8);  v += __shfl_xor(v, 16); v += __shfl_xor(v, 32);
  if (lane == 0) ws2[ls] = v;
}

// ---------------- final global RMS scale, in place ----------------
template<typename T>
__global__ void k_scale(const float* __restrict__ ws2, T* __restrict__ out,
                        const int* __restrict__ flag) {
  if (flag[0] != dtid<T>()) return;
  int i = blockIdx.x*blockDim.x + threadIdx.x;
  if (i >= 3360000) return;
  int ls = (i < 320000) ? 0 : (i < 1040000) ? 1 : (i < 1760000) ? 2 : (i < 2560000) ? 3 : 4;
  float scale = rsqrtf(ws2[ls] / (float)c_numel[ls] + 1e-12f);
  stv(out, OY + i, ldv((const T*)out, OY + i) * scale);
}

template<typename T>
static void launch_chain(void* const* d_in, T* out, float* wsf, int* wsi,
                         Ptrs15 cg, LinP lp, bool big, hipStream_t stream) {
  const T* rb0 = (const T*)d_in[0];
  const T* rb1 = (const T*)d_in[1];
  const T* rb2 = (const T*)d_in[2];
  const T* sh0 = (const T*)d_in[3];
  const T* sh1 = (const T*)d_in[4];
  const T* sh2 = (const T*)d_in[5];
  const T* emb = (const T*)d_in[6];
  const T* f0  = (const T*)d_in[7];
  const T* f1  = (const T*)d_in[8];
  const T* f2  = (const T*)d_in[9];
  const int* neighbors = (const int*)d_in[36];
  const int* flag = wsi + IFLAG;

  k_cg<T><<<3, 256, 0, stream>>>(cg, wsf, flag);
  if (big) {
    k_main<T,0><<<N_ATOMS, 256, 0, stream>>>(rb0, rb1, rb2, sh0, sh1, sh2, emb, f0, f1, f2,
        neighbors, wsi+IOFFS, wsi+IELIST, wsf+SCG, wsf+SS1P, nullptr, nullptr,
        wsf+SXACC, lp, out, flag);
    k_red1<<<296, 64, 0, stream>>>(wsf+SS1P, wsf+SINV);
    k_lin<T><<<N_ATOMS, 256, 0, stream>>>(wsf+SXACC, wsf+SINV, lp, out, wsf+SS2P, flag);
  } else {
    k_main<T,1><<<N_ATOMS, 256, 0, stream>>>(rb0, rb1, rb2, sh0, sh1, sh2, emb, f0, f1, f2,
        neighbors, wsi+IOFFS, wsi+IELIST, wsf+SCG, wsf+SS1P, nullptr, nullptr,
        nullptr, lp, out, flag);
    k_red1<<<296, 64, 0, stream>>>(wsf+SS1P, wsf+SINV);
    k_main<T,2><<<N_ATOMS, 256, 0, stream>>>(rb0, rb1, rb2, sh0, sh1, sh2, emb, f0, f1, f2,
        neighbors, wsi+IOFFS, wsi+IELIST, wsf+SCG, nullptr, wsf+SINV, wsf+SS2P,
        nullptr, lp, out, flag);
  }
  k_red2<<<5, 64, 0, stream>>>(wsf+SS2P, wsf+SWS2);
  k_scale<T><<<(3360000+255)/256, 256, 0, stream>>>(wsf+SWS2, out, flag);
}

extern "C" void kernel_launch(void* const* d_in, const int* in_sizes, int n_in,
                              void* d_out, int out_size, void* d_ws, size_t ws_size,
                              hipStream_t stream) {
  float* wsf = (float*)d_ws;
  int*   wsi = (int*)(wsf + SINTS);
  const int* centers   = (const int*)d_in[35];
  const int* neighbors = (const int*)d_in[36];
  bool big = ws_size >= (size_t)BIG_FLOATS * 4;

  Ptrs15 cg;
  for (int i = 0; i < 15; ++i) cg.p[i] = d_in[10+i];
  LinP lp;
  lp.W[0] = d_in[25]; lp.B[0] = d_in[26];
  lp.W[1] = d_in[27]; lp.B[1] = d_in[28];
  lp.W[2] = d_in[29]; lp.B[2] = d_in[30];
  lp.W[3] = d_in[31]; lp.B[3] = d_in[32];
  lp.W[4] = d_in[33]; lp.B[4] = d_in[34];

  k_probe<<<1, 64, 0, stream>>>((const unsigned short*)d_in[0],
                                (const unsigned short*)d_in[6], wsi + IFLAG);
  k_zero<<<154, 256, 0, stream>>>(wsf, wsi);
  k_hist<<<(N_EDGES+255)/256, 256, 0, stream>>>(centers, wsi+ICOUNT);
  k_scan<<<1, 1024, 0, stream>>>(wsi+ICOUNT, wsi+IOFFS);
  if (big) {
    k_scatter2<<<(N_EDGES+255)/256, 256, 0, stream>>>(centers, neighbors, wsi+IOFFS,
                                                      wsi+ICURS, (int2*)(wsi+IELIST));
  } else {
    k_scatter<<<(N_EDGES+255)/256, 256, 0, stream>>>(centers, wsi+IOFFS, wsi+ICURS, wsi+IELIST);
  }

  launch_chain<bf16 >(d_in, (bf16*)d_out,  wsf, wsi, cg, lp, big, stream);
  launch_chain<float>(d_in, (float*)d_out, wsf, wsi, cg, lp, big, stream);
}